// Round 4
// baseline (1107.652 us; speedup 1.0000x reference)
//
#include <hip/hip_runtime.h>

// D-MPNN forward for MI355X (gfx950).
// R4: split KP=256 weight staging into 2x64KB halves -> 2 blocks/CU (was 1 at
// 128KB); vectorized padcvt.

#define DI __device__ __forceinline__

typedef __bf16 bf16x8 __attribute__((ext_vector_type(8)));
typedef float f32x8 __attribute__((ext_vector_type(8)));
typedef float f32x16 __attribute__((ext_vector_type(16)));
typedef unsigned short u16x8 __attribute__((ext_vector_type(8)));

static constexpr int cNA = 120001;
static constexpr int cNB = 260001;
static constexpr int cAF = 133;
static constexpr int cBF = 147;
static constexpr int KP_F = 160;   // padded feature K (both 147->160 and 133->160)

DI bf16x8 ldbf8(const unsigned short* p) {
  return __builtin_bit_cast(bf16x8, *reinterpret_cast<const u16x8*>(p));
}
DI void stbf8(unsigned short* p, bf16x8 v) {
  *reinterpret_cast<u16x8*>(p) = __builtin_bit_cast(u16x8, v);
}
DI f32x8 up8(bf16x8 v) { return __builtin_convertvector(v, f32x8); }
DI f32x8 up8u(u16x8 v) { return up8(__builtin_bit_cast(bf16x8, v)); }
DI bf16x8 dn8(f32x8 v) { return __builtin_convertvector(v, bf16x8); }
DI float bfh2f(unsigned short h) { return __builtin_bit_cast(float, (unsigned)h << 16); }
DI unsigned short f2bfh(float f) {
  __bf16 b = (__bf16)f;
  return __builtin_bit_cast(unsigned short, b);
}

// ---------------- pre-convert kernels ----------------
// 8 elements per thread: two dwordx4-class reads, one 16-B store.
__global__ void k_padcvt8(const float* __restrict__ in, unsigned short* __restrict__ out,
                          int nrows, int kin, int kpad) {
  long long total = (long long)nrows * (kpad / 8);
  long long i = (long long)blockIdx.x * blockDim.x + threadIdx.x;
  if (i >= total) return;
  int row = (int)(i / (kpad / 8));
  int k0 = (int)(i - (long long)row * (kpad / 8)) * 8;
  const float* src = in + (long long)row * kin;
  f32x8 v;
#pragma unroll
  for (int e = 0; e < 8; e++) v[e] = (k0 + e < kin) ? src[k0 + e] : 0.f;
  stbf8(out + (long long)row * kpad + k0, dn8(v));
}

// out[n][k] = W[k+rowoff][n], zero-padded past K
__global__ void k_transw(const float* __restrict__ W, unsigned short* __restrict__ out,
                         int K, int kpad, int rowoff) {
  int i = blockIdx.x * blockDim.x + threadIdx.x;
  if (i >= 256 * kpad) return;
  int n = i / kpad, k = i - n * kpad;
  float v = (k < K) ? W[(long long)(k + rowoff) * 256 + n] : 0.f;
  out[i] = f2bfh(v);
}

// ---------------- gather-sum over a2b (6 neighbors) ----------------
__global__ __launch_bounds__(256) void k_gathersum(
    const unsigned short* __restrict__ src, const int* __restrict__ a2b,
    unsigned short* __restrict__ out, int relu_flag) {
  int tid = blockIdx.x * 256 + threadIdx.x;
  if (tid >= cNA * 16) return;
  int atom = tid >> 4, ch = tid & 15;            // 16 threads per atom, 16 cols each
  const int* ab = a2b + (long long)atom * 6;
  int bidx[6];
#pragma unroll
  for (int j = 0; j < 6; j++) bidx[j] = ab[j];
  u16x8 r0[6], r1[6];
#pragma unroll
  for (int j = 0; j < 6; j++) {
    const unsigned short* p = src + (long long)bidx[j] * 256 + ch * 16;
    r0[j] = *reinterpret_cast<const u16x8*>(p);
    r1[j] = *reinterpret_cast<const u16x8*>(p + 8);
  }
  f32x8 lo = {0.f,0.f,0.f,0.f,0.f,0.f,0.f,0.f}, hi = lo;
#pragma unroll
  for (int j = 0; j < 6; j++) {
    f32x8 x0 = up8u(r0[j]);
    f32x8 x1 = up8u(r1[j]);
    if (relu_flag) {
#pragma unroll
      for (int e = 0; e < 8; e++) { x0[e] = fmaxf(x0[e], 0.f); x1[e] = fmaxf(x1[e], 0.f); }
    }
#pragma unroll
    for (int e = 0; e < 8; e++) { lo[e] += x0[e]; hi[e] += x1[e]; }
  }
  unsigned short* q = out + (long long)atom * 256 + ch * 16;
  stbf8(q, dn8(lo));
  stbf8(q + 8, dn8(hi));
}

// ---------------- MFMA GEMM family ----------------
// Each block: 16 waves, 512 rows (32/wave), N=256 (8 col-blocks of 32).
// Wt [256][KP] staged in LDS in fragment-contiguous layout, in NSTAGE stages of
// CBS col-blocks (KP=256: 2 stages x 64KB -> 2 blocks/CU; KP=160: 1 x 80KB).
//   within a stage: frag (cb_l,f) at (cb_l*NF+f)*512 ushorts; lane reads
//   lds + frag*512 + lane*8 (stride-1, no bank conflicts).
enum { MODE_BF16OUT = 0, MODE_MSG = 2, MODE_FINAL = 3 };

template <int KP, int MODE, bool RELU_SRC>
__global__ __launch_bounds__(1024) void k_gemm(
    const unsigned short* __restrict__ A,     // direct A [nrows][KP] bf16 (or amsg for MODE_MSG)
    const unsigned short* __restrict__ Msg,   // MODE_MSG: message source [NB][256] bf16
    const int* __restrict__ b2a, const int* __restrict__ b2revb,
    const unsigned short* __restrict__ Wt,    // [256][KP] bf16 (W transposed)
    const unsigned short* __restrict__ Cbf,   // MODE_MSG: inp bf16 ; MODE_FINAL: pf bf16
    const float* __restrict__ bias,           // MODE_FINAL: b_o
    unsigned short* __restrict__ OutBf, int nrows) {
  constexpr int NF = KP / 16;                 // K-frags per col-block
  constexpr int NCB = 8;                      // 256/32 col-blocks total
  constexpr int NSTAGE = (KP == 256) ? 2 : 1;
  constexpr int CBS = NCB / NSTAGE;           // col-blocks per stage
  __shared__ unsigned short lds[CBS * NF * 512];

  const int tid = threadIdx.x;
  const int lane = tid & 63, wid = tid >> 6;
  const int rbase = blockIdx.x * 512 + wid * 32;
  const int rA = rbase + (lane & 31);
  const int rS = rA < nrows ? rA : 0;
  const int kg = lane >> 5;  // 0/1: which 8-wide K half of the 16-K fragment

  bf16x8 af[NF];
  if (MODE == MODE_MSG) {
    int ib = b2a[rS];
    int irv = b2revb[rS];
    const unsigned short* pa = A + (long long)ib * 256;
    const unsigned short* pm = Msg + (long long)irv * 256;
    u16x8 rawa[NF], rawm[NF];
#pragma unroll
    for (int f = 0; f < NF; f++) {
      int off = f * 16 + kg * 8;
      rawa[f] = *reinterpret_cast<const u16x8*>(pa + off);
      rawm[f] = *reinterpret_cast<const u16x8*>(pm + off);
    }
#pragma unroll
    for (int f = 0; f < NF; f++) {
      f32x8 xa = up8u(rawa[f]);
      f32x8 xm = up8u(rawm[f]);
      if (RELU_SRC) {
#pragma unroll
      for (int e = 0; e < 8; e++) xm[e] = fmaxf(xm[e], 0.f);
      }
      af[f] = dn8(xa - xm);
    }
  } else {
    const unsigned short* pa = A + (long long)rS * KP;
#pragma unroll
    for (int f = 0; f < NF; f++) af[f] = ldbf8(pa + f * 16 + kg * 8);
  }

  // hoist bias loads (MODE_FINAL)
  float bv[NCB];
  if (MODE == MODE_FINAL) {
#pragma unroll
    for (int cb = 0; cb < NCB; cb++) bv[cb] = bias[cb * 32 + (lane & 31)];
  }

#pragma unroll 1
  for (int stage = 0; stage < NSTAGE; stage++) {
    if (stage) __syncthreads();   // previous stage's MFMA reads must finish
    for (int c = tid; c < CBS * NF * 64; c += 1024) {
      int frag = c >> 6, slot = c & 63;
      int cb_l = frag / NF, f = frag - cb_l * NF;
      int col = (stage * CBS + cb_l) * 32 + (slot & 31);
      int koff = f * 16 + (slot >> 5) * 8;    // ushort units within row
      *reinterpret_cast<u16x8*>(lds + c * 8) =
          *reinterpret_cast<const u16x8*>(Wt + (long long)col * KP + koff);
    }
    __syncthreads();

#pragma unroll 1
    for (int cb_l = 0; cb_l < CBS; cb_l++) {
      const int cb = stage * CBS + cb_l;
      const int col = cb * 32 + (lane & 31);
      const int rb2 = rbase + 4 * kg;

      // (a) batch-issue C loads as raw ushorts; waitcnt sinks past the MFMA chain
      unsigned short craw[16];
      if (MODE == MODE_MSG || MODE == MODE_FINAL) {
#pragma unroll
        for (int q = 0; q < 16; q++) {
          int row = rb2 + (q & 3) + 8 * (q >> 2);
          int rowc = row < nrows ? row : 0;
          craw[q] = Cbf[(long long)rowc * 256 + col];
        }
      }

      // (b) LDS B-frags + MFMA chain
      f32x16 acc;
#pragma unroll
      for (int q = 0; q < 16; q++) acc[q] = 0.f;
      const unsigned short* lb = lds + cb_l * NF * 512 + lane * 8;
#pragma unroll
      for (int f = 0; f < NF; f++) {
        bf16x8 b = ldbf8(lb + f * 512);
        acc = __builtin_amdgcn_mfma_f32_32x32x16_bf16(af[f], b, acc, 0, 0, 0);
      }

      // (c) merge + store. C/D layout: col=lane&31, row=(q&3)+8*(q>>2)+4*(lane>>5)
#pragma unroll
      for (int q = 0; q < 16; q++) {
        int row = rb2 + (q & 3) + 8 * (q >> 2);
        if (row >= nrows) continue;
        float v = acc[q];
        long long idx = (long long)row * 256 + col;
        if (MODE == MODE_BF16OUT) {
          OutBf[idx] = f2bfh(v);
        } else if (MODE == MODE_MSG) {
          v += bfh2f(craw[q]);
          v = fmaxf(v, 0.f);
          OutBf[idx] = f2bfh(v);
        } else {  // MODE_FINAL
          v += bfh2f(craw[q]) + bv[cb];
          v = fmaxf(v, 0.f);
          OutBf[idx] = f2bfh(v);
        }
      }
    }
  }
}

// ---------------- molecule mean-pool (bf16 in, fp32 out) ----------------
__global__ __launch_bounds__(256) void k_meanpool(const unsigned short* __restrict__ ah,
                                                  float* __restrict__ out) {
  int m = blockIdx.x, c = threadIdx.x;
  unsigned short r[20];
#pragma unroll
  for (int i = 0; i < 20; i++) r[i] = ah[(long long)(1 + m * 20 + i) * 256 + c];
  float s = 0.f;
#pragma unroll
  for (int i = 0; i < 20; i++) s += bfh2f(r[i]);
  out[(long long)m * 256 + c] = s * 0.05f;
}

extern "C" void kernel_launch(void* const* d_in, const int* in_sizes, int n_in,
                              void* d_out, int out_size, void* d_ws, size_t ws_size,
                              hipStream_t stream) {
  const float* f_atoms = (const float*)d_in[0];
  const float* f_bonds = (const float*)d_in[1];
  const int* a2b = (const int*)d_in[2];
  const int* b2a = (const int*)d_in[3];
  const int* b2revb = (const int*)d_in[4];
  const float* W_i = (const float*)d_in[5];
  const float* W_h = (const float*)d_in[6];
  const float* W_o = (const float*)d_in[7];
  const float* b_o = (const float*)d_in[8];
  float* out = (float*)d_out;

  char* ws = (char*)d_ws;
  size_t off = 0;
  auto alloc = [&](size_t b) { size_t o = off; off += (b + 1023) & ~(size_t)1023; return o; };
  size_t o_fb = alloc((size_t)cNB * KP_F * 2);     // fb16; later reused for amsg (61.4MB<=83.2MB)
  size_t o_fa = alloc((size_t)cNA * KP_F * 2);     // fa16
  size_t o_inp = alloc((size_t)cNB * 256 * 2);     // inp bf16
  size_t o_bufA = alloc((size_t)cNB * 256 * 2);    // msgA ; later pf (bf16 NA*256)
  size_t o_bufB = alloc((size_t)cNB * 256 * 2);    // msgB ; later ah (bf16 NA*256)
  size_t o_wti = alloc((size_t)256 * KP_F * 2);
  size_t o_wth = alloc((size_t)256 * 256 * 2);
  size_t o_wo1 = alloc((size_t)256 * KP_F * 2);
  size_t o_wo2 = alloc((size_t)256 * 256 * 2);

  unsigned short* fb16 = (unsigned short*)(ws + o_fb);
  unsigned short* amsg = (unsigned short*)(ws + o_fb);  // overlays fb16 after K1
  unsigned short* fa16 = (unsigned short*)(ws + o_fa);
  unsigned short* inp = (unsigned short*)(ws + o_inp);
  unsigned short* msgA = (unsigned short*)(ws + o_bufA);
  unsigned short* msgB = (unsigned short*)(ws + o_bufB);
  unsigned short* pf = (unsigned short*)(ws + o_bufA);
  unsigned short* ah = (unsigned short*)(ws + o_bufB);
  unsigned short* Wti = (unsigned short*)(ws + o_wti);
  unsigned short* Wth = (unsigned short*)(ws + o_wth);
  unsigned short* Wto1 = (unsigned short*)(ws + o_wo1);
  unsigned short* Wto2 = (unsigned short*)(ws + o_wo2);

  dim3 b256(256);
  {
    long long t = (long long)cNB * (KP_F / 8);
    k_padcvt8<<<(unsigned)((t + 255) / 256), b256, 0, stream>>>(f_bonds, fb16, cNB, cBF, KP_F);
  }
  {
    long long t = (long long)cNA * (KP_F / 8);
    k_padcvt8<<<(unsigned)((t + 255) / 256), b256, 0, stream>>>(f_atoms, fa16, cNA, cAF, KP_F);
  }
  k_transw<<<(256 * KP_F + 255) / 256, b256, 0, stream>>>(W_i, Wti, cBF, KP_F, 0);
  k_transw<<<(256 * 256 + 255) / 256, b256, 0, stream>>>(W_h, Wth, 256, 256, 0);
  k_transw<<<(256 * KP_F + 255) / 256, b256, 0, stream>>>(W_o, Wto1, cAF, KP_F, 0);
  k_transw<<<(256 * 256 + 255) / 256, b256, 0, stream>>>(W_o, Wto2, 256, 256, cAF);

  const int gB = (cNB + 511) / 512;
  const int gA = (cNA + 511) / 512;
  const int gS = (cNA * 16 + 255) / 256;

  // K1: inp = fb16 @ W_i
  k_gemm<KP_F, MODE_BF16OUT, false><<<gB, 1024, 0, stream>>>(
      fb16, nullptr, nullptr, nullptr, Wti, nullptr, nullptr, inp, cNB);
  // iter 1
  k_gathersum<<<gS, b256, 0, stream>>>(inp, a2b, amsg, 1);
  k_gemm<256, MODE_MSG, true><<<gB, 1024, 0, stream>>>(
      amsg, inp, b2a, b2revb, Wth, inp, nullptr, msgA, cNB);
  // iter 2
  k_gathersum<<<gS, b256, 0, stream>>>(msgA, a2b, amsg, 0);
  k_gemm<256, MODE_MSG, false><<<gB, 1024, 0, stream>>>(
      amsg, msgA, b2a, b2revb, Wth, inp, nullptr, msgB, cNB);
  // readout
  k_gathersum<<<gS, b256, 0, stream>>>(msgB, a2b, amsg, 0);
  k_gemm<KP_F, MODE_BF16OUT, false><<<gA, 1024, 0, stream>>>(
      fa16, nullptr, nullptr, nullptr, Wto1, nullptr, nullptr, pf, cNA);
  k_gemm<256, MODE_FINAL, false><<<gA, 1024, 0, stream>>>(
      amsg, nullptr, nullptr, nullptr, Wto2, pf, b_o, ah, cNA);
  k_meanpool<<<6000, b256, 0, stream>>>(ah, out);
}

// Round 5
// 941.198 us; speedup vs baseline: 1.1769x; 1.1769x over previous
//
#include <hip/hip_runtime.h>

// D-MPNN forward for MI355X (gfx950).
// R5: GEMM re-geometried to mfma 16x16x32 (16 rows/wave) so the whole kernel
// fits in 64 VGPRs -> __launch_bounds__(1024,8) -> 2 blocks/CU (32 waves/CU),
// with 2-stage 64KB weight staging (col-halves). R4's spill came from 32x32
// geometry (af=64 regs) at a 64-reg budget.

#define DI __device__ __forceinline__

typedef __bf16 bf16x8 __attribute__((ext_vector_type(8)));
typedef float f32x4 __attribute__((ext_vector_type(4)));
typedef float f32x8 __attribute__((ext_vector_type(8)));
typedef unsigned short u16x8 __attribute__((ext_vector_type(8)));

static constexpr int cNA = 120001;
static constexpr int cNB = 260001;
static constexpr int cAF = 133;
static constexpr int cBF = 147;
static constexpr int KP_F = 160;   // padded feature K (147->160 and 133->160)

DI bf16x8 ldbf8(const unsigned short* p) {
  return __builtin_bit_cast(bf16x8, *reinterpret_cast<const u16x8*>(p));
}
DI void stbf8(unsigned short* p, bf16x8 v) {
  *reinterpret_cast<u16x8*>(p) = __builtin_bit_cast(u16x8, v);
}
DI f32x8 up8(bf16x8 v) { return __builtin_convertvector(v, f32x8); }
DI f32x8 up8u(u16x8 v) { return up8(__builtin_bit_cast(bf16x8, v)); }
DI bf16x8 dn8(f32x8 v) { return __builtin_convertvector(v, bf16x8); }
DI float bfh2f(unsigned short h) { return __builtin_bit_cast(float, (unsigned)h << 16); }
DI unsigned short f2bfh(float f) {
  __bf16 b = (__bf16)f;
  return __builtin_bit_cast(unsigned short, b);
}

// ---------------- pre-convert kernels ----------------
__global__ void k_padcvt8(const float* __restrict__ in, unsigned short* __restrict__ out,
                          int nrows, int kin, int kpad) {
  long long total = (long long)nrows * (kpad / 8);
  long long i = (long long)blockIdx.x * blockDim.x + threadIdx.x;
  if (i >= total) return;
  int row = (int)(i / (kpad / 8));
  int k0 = (int)(i - (long long)row * (kpad / 8)) * 8;
  const float* src = in + (long long)row * kin;
  f32x8 v;
#pragma unroll
  for (int e = 0; e < 8; e++) v[e] = (k0 + e < kin) ? src[k0 + e] : 0.f;
  stbf8(out + (long long)row * kpad + k0, dn8(v));
}

// out[n][k] = W[k+rowoff][n], zero-padded past K
__global__ void k_transw(const float* __restrict__ W, unsigned short* __restrict__ out,
                         int K, int kpad, int rowoff) {
  int i = blockIdx.x * blockDim.x + threadIdx.x;
  if (i >= 256 * kpad) return;
  int n = i / kpad, k = i - n * kpad;
  float v = (k < K) ? W[(long long)(k + rowoff) * 256 + n] : 0.f;
  out[i] = f2bfh(v);
}

// ---------------- gather-sum over a2b (6 neighbors) ----------------
__global__ __launch_bounds__(256) void k_gathersum(
    const unsigned short* __restrict__ src, const int* __restrict__ a2b,
    unsigned short* __restrict__ out, int relu_flag) {
  int tid = blockIdx.x * 256 + threadIdx.x;
  if (tid >= cNA * 16) return;
  int atom = tid >> 4, ch = tid & 15;            // 16 threads per atom, 16 cols each
  const int* ab = a2b + (long long)atom * 6;
  int bidx[6];
#pragma unroll
  for (int j = 0; j < 6; j++) bidx[j] = ab[j];
  u16x8 r0[6], r1[6];
#pragma unroll
  for (int j = 0; j < 6; j++) {
    const unsigned short* p = src + (long long)bidx[j] * 256 + ch * 16;
    r0[j] = *reinterpret_cast<const u16x8*>(p);
    r1[j] = *reinterpret_cast<const u16x8*>(p + 8);
  }
  f32x8 lo = {0.f,0.f,0.f,0.f,0.f,0.f,0.f,0.f}, hi = lo;
#pragma unroll
  for (int j = 0; j < 6; j++) {
    f32x8 x0 = up8u(r0[j]);
    f32x8 x1 = up8u(r1[j]);
    if (relu_flag) {
#pragma unroll
      for (int e = 0; e < 8; e++) { x0[e] = fmaxf(x0[e], 0.f); x1[e] = fmaxf(x1[e], 0.f); }
    }
#pragma unroll
    for (int e = 0; e < 8; e++) { lo[e] += x0[e]; hi[e] += x1[e]; }
  }
  unsigned short* q = out + (long long)atom * 256 + ch * 16;
  stbf8(q, dn8(lo));
  stbf8(q + 8, dn8(hi));
}

// ---------------- MFMA GEMM family (16x16x32) ----------------
// Block: 16 waves x 16 rows = 256 rows; N=256 as 16 col-tiles of 16.
// 2 stages of 8 col-tiles; per-stage LDS = 8*NF KB (KP=256: 64KB, KP=160: 40KB).
// Fragment-contiguous LDS: frag (ctl,f) at (ctl*NF+f)*512 ushorts; lane reads
// frag_base + lane*8 (stride-1, conflict-free).
// Layouts (m89-family): A: row=lane&15, k=(lane>>4)*8+j. B: col=lane&15, same k.
// C/D: col=lane&15, row=(lane>>4)*4+q.
enum { MODE_BF16OUT = 0, MODE_MSG = 2, MODE_FINAL = 3 };

template <int KP, int MODE, bool RELU_SRC>
__global__ __launch_bounds__(1024, 8) void k_gemm(
    const unsigned short* __restrict__ A,     // direct A [nrows][KP] (or amsg for MSG)
    const unsigned short* __restrict__ Msg,   // MSG: message source [NB][256]
    const int* __restrict__ b2a, const int* __restrict__ b2revb,
    const unsigned short* __restrict__ Wt,    // [256][KP] (W transposed)
    const unsigned short* __restrict__ Cbf,   // MSG: inp ; FINAL: pf
    const float* __restrict__ bias,           // FINAL: b_o
    unsigned short* __restrict__ OutBf, int nrows) {
  constexpr int NF = KP / 32;                 // K-frags per col-tile
  constexpr int CTS = 8;                      // col-tiles per stage
  __shared__ unsigned short lds[CTS * NF * 512];

  const int tid = threadIdx.x;
  const int lane = tid & 63, wid = tid >> 6;
  const int wrow0 = blockIdx.x * 256 + wid * 16;
  const int rA = wrow0 + (lane & 15);
  const int rS = rA < nrows ? rA : 0;
  const int koff = (lane >> 4) * 8;           // k-chunk within 32-K fragment

  // ---- A fragments (held across both stages) ----
  bf16x8 af[NF];
  if (MODE == MODE_MSG) {
    int ib = b2a[rS];
    int irv = b2revb[rS];
    const unsigned short* pa = A + (long long)ib * 256;
    const unsigned short* pm = Msg + (long long)irv * 256;
    // two batches of 4 frags to cap register pressure
#pragma unroll
    for (int h = 0; h < NF / 4; h++) {
      u16x8 rawa[4], rawm[4];
#pragma unroll
      for (int t = 0; t < 4; t++) {
        int off = (h * 4 + t) * 32 + koff;
        rawa[t] = *reinterpret_cast<const u16x8*>(pa + off);
        rawm[t] = *reinterpret_cast<const u16x8*>(pm + off);
      }
#pragma unroll
      for (int t = 0; t < 4; t++) {
        f32x8 xa = up8u(rawa[t]);
        f32x8 xm = up8u(rawm[t]);
        if (RELU_SRC) {
#pragma unroll
          for (int e = 0; e < 8; e++) xm[e] = fmaxf(xm[e], 0.f);
        }
        af[h * 4 + t] = dn8(xa - xm);
      }
    }
  } else {
    const unsigned short* pa = A + (long long)rS * KP;
#pragma unroll
    for (int f = 0; f < NF; f++) af[f] = ldbf8(pa + f * 32 + koff);
  }

#pragma unroll 1
  for (int stage = 0; stage < 2; stage++) {
    if (stage) __syncthreads();   // previous stage's LDS reads must finish
    for (int c = tid; c < CTS * NF * 64; c += 1024) {
      int frag = c >> 6, slot = c & 63;
      int ctl = frag / NF, f = frag - ctl * NF;
      int col = stage * 128 + ctl * 16 + (slot & 15);
      int ko = f * 32 + (slot >> 4) * 8;
      *reinterpret_cast<u16x8*>(lds + c * 8) =
          *reinterpret_cast<const u16x8*>(Wt + (long long)col * KP + ko);
    }
    __syncthreads();

#pragma unroll 1
    for (int ctl = 0; ctl < CTS; ctl++) {
      const int ct = stage * CTS + ctl;
      const int col = ct * 16 + (lane & 15);
      const int r0 = wrow0 + (lane >> 4) * 4;

      // batch C loads (issue before MFMA chain; waitcnt sinks past it)
      unsigned short craw[4];
      if (MODE == MODE_MSG || MODE == MODE_FINAL) {
#pragma unroll
        for (int q = 0; q < 4; q++) {
          int row = r0 + q;
          int rowc = row < nrows ? row : 0;
          craw[q] = Cbf[(long long)rowc * 256 + col];
        }
      }
      float bvv = 0.f;
      if (MODE == MODE_FINAL) bvv = bias[col];

      f32x4 acc = {0.f, 0.f, 0.f, 0.f};
      const unsigned short* lb = lds + ctl * NF * 512 + lane * 8;
#pragma unroll
      for (int f = 0; f < NF; f++) {
        bf16x8 b = ldbf8(lb + f * 512);
        acc = __builtin_amdgcn_mfma_f32_16x16x32_bf16(af[f], b, acc, 0, 0, 0);
      }

#pragma unroll
      for (int q = 0; q < 4; q++) {
        int row = r0 + q;
        if (row >= nrows) continue;
        float v = acc[q];
        long long idx = (long long)row * 256 + col;
        if (MODE == MODE_BF16OUT) {
          OutBf[idx] = f2bfh(v);
        } else if (MODE == MODE_MSG) {
          v += bfh2f(craw[q]);
          v = fmaxf(v, 0.f);
          OutBf[idx] = f2bfh(v);
        } else {  // MODE_FINAL
          v += bfh2f(craw[q]) + bvv;
          v = fmaxf(v, 0.f);
          OutBf[idx] = f2bfh(v);
        }
      }
    }
  }
}

// ---------------- molecule mean-pool (bf16 in, fp32 out) ----------------
__global__ __launch_bounds__(256) void k_meanpool(const unsigned short* __restrict__ ah,
                                                  float* __restrict__ out) {
  int m = blockIdx.x, c = threadIdx.x;
  unsigned short r[20];
#pragma unroll
  for (int i = 0; i < 20; i++) r[i] = ah[(long long)(1 + m * 20 + i) * 256 + c];
  float s = 0.f;
#pragma unroll
  for (int i = 0; i < 20; i++) s += bfh2f(r[i]);
  out[(long long)m * 256 + c] = s * 0.05f;
}

extern "C" void kernel_launch(void* const* d_in, const int* in_sizes, int n_in,
                              void* d_out, int out_size, void* d_ws, size_t ws_size,
                              hipStream_t stream) {
  const float* f_atoms = (const float*)d_in[0];
  const float* f_bonds = (const float*)d_in[1];
  const int* a2b = (const int*)d_in[2];
  const int* b2a = (const int*)d_in[3];
  const int* b2revb = (const int*)d_in[4];
  const float* W_i = (const float*)d_in[5];
  const float* W_h = (const float*)d_in[6];
  const float* W_o = (const float*)d_in[7];
  const float* b_o = (const float*)d_in[8];
  float* out = (float*)d_out;

  char* ws = (char*)d_ws;
  size_t off = 0;
  auto alloc = [&](size_t b) { size_t o = off; off += (b + 1023) & ~(size_t)1023; return o; };
  size_t o_fb = alloc((size_t)cNB * KP_F * 2);     // fb16; later reused for amsg
  size_t o_fa = alloc((size_t)cNA * KP_F * 2);     // fa16
  size_t o_inp = alloc((size_t)cNB * 256 * 2);     // inp bf16
  size_t o_bufA = alloc((size_t)cNB * 256 * 2);    // msgA ; later pf (bf16 NA*256)
  size_t o_bufB = alloc((size_t)cNB * 256 * 2);    // msgB ; later ah (bf16 NA*256)
  size_t o_wti = alloc((size_t)256 * KP_F * 2);
  size_t o_wth = alloc((size_t)256 * 256 * 2);
  size_t o_wo1 = alloc((size_t)256 * KP_F * 2);
  size_t o_wo2 = alloc((size_t)256 * 256 * 2);

  unsigned short* fb16 = (unsigned short*)(ws + o_fb);
  unsigned short* amsg = (unsigned short*)(ws + o_fb);  // overlays fb16 after K1
  unsigned short* fa16 = (unsigned short*)(ws + o_fa);
  unsigned short* inp = (unsigned short*)(ws + o_inp);
  unsigned short* msgA = (unsigned short*)(ws + o_bufA);
  unsigned short* msgB = (unsigned short*)(ws + o_bufB);
  unsigned short* pf = (unsigned short*)(ws + o_bufA);
  unsigned short* ah = (unsigned short*)(ws + o_bufB);
  unsigned short* Wti = (unsigned short*)(ws + o_wti);
  unsigned short* Wth = (unsigned short*)(ws + o_wth);
  unsigned short* Wto1 = (unsigned short*)(ws + o_wo1);
  unsigned short* Wto2 = (unsigned short*)(ws + o_wo2);

  dim3 b256(256);
  {
    long long t = (long long)cNB * (KP_F / 8);
    k_padcvt8<<<(unsigned)((t + 255) / 256), b256, 0, stream>>>(f_bonds, fb16, cNB, cBF, KP_F);
  }
  {
    long long t = (long long)cNA * (KP_F / 8);
    k_padcvt8<<<(unsigned)((t + 255) / 256), b256, 0, stream>>>(f_atoms, fa16, cNA, cAF, KP_F);
  }
  k_transw<<<(256 * KP_F + 255) / 256, b256, 0, stream>>>(W_i, Wti, cBF, KP_F, 0);
  k_transw<<<(256 * 256 + 255) / 256, b256, 0, stream>>>(W_h, Wth, 256, 256, 0);
  k_transw<<<(256 * KP_F + 255) / 256, b256, 0, stream>>>(W_o, Wto1, cAF, KP_F, 0);
  k_transw<<<(256 * 256 + 255) / 256, b256, 0, stream>>>(W_o, Wto2, 256, 256, cAF);

  const int gB = (cNB + 255) / 256;
  const int gA = (cNA + 255) / 256;
  const int gS = (cNA * 16 + 255) / 256;

  // K1: inp = fb16 @ W_i
  k_gemm<KP_F, MODE_BF16OUT, false><<<gB, 1024, 0, stream>>>(
      fb16, nullptr, nullptr, nullptr, Wti, nullptr, nullptr, inp, cNB);
  // iter 1
  k_gathersum<<<gS, b256, 0, stream>>>(inp, a2b, amsg, 1);
  k_gemm<256, MODE_MSG, true><<<gB, 1024, 0, stream>>>(
      amsg, inp, b2a, b2revb, Wth, inp, nullptr, msgA, cNB);
  // iter 2
  k_gathersum<<<gS, b256, 0, stream>>>(msgA, a2b, amsg, 0);
  k_gemm<256, MODE_MSG, false><<<gB, 1024, 0, stream>>>(
      amsg, msgA, b2a, b2revb, Wth, inp, nullptr, msgB, cNB);
  // readout
  k_gathersum<<<gS, b256, 0, stream>>>(msgB, a2b, amsg, 0);
  k_gemm<KP_F, MODE_BF16OUT, false><<<gA, 1024, 0, stream>>>(
      fa16, nullptr, nullptr, nullptr, Wto1, nullptr, nullptr, pf, cNA);
  k_gemm<256, MODE_FINAL, false><<<gA, 1024, 0, stream>>>(
      amsg, nullptr, nullptr, nullptr, Wto2, pf, b_o, ah, cNA);
  k_meanpool<<<6000, b256, 0, stream>>>(ah, out);
}

// Round 8
// 916.371 us; speedup vs baseline: 1.2087x; 1.0271x over previous
//
#include <hip/hip_runtime.h>

// D-MPNN forward for MI355X (gfx950).
// R6 (2nd resubmit after GPU-acquisition timeouts): MFMA operand swap (compute
// D^T = W·X^T) so each lane owns one output row x 4 consecutive cols -> 8-B
// vector C-loads/stores (was 2-B scalar, 1.83x write amplification), float4
// bias, 1-tile C-load prefetch pipeline.

#define DI __device__ __forceinline__

typedef __bf16 bf16x8 __attribute__((ext_vector_type(8)));
typedef float f32x4 __attribute__((ext_vector_type(4)));
typedef float f32x8 __attribute__((ext_vector_type(8)));
typedef unsigned short u16x4 __attribute__((ext_vector_type(4)));
typedef unsigned short u16x8 __attribute__((ext_vector_type(8)));

static constexpr int cNA = 120001;
static constexpr int cNB = 260001;
static constexpr int cAF = 133;
static constexpr int cBF = 147;
static constexpr int KP_F = 160;   // padded feature K (147->160 and 133->160)

DI bf16x8 ldbf8(const unsigned short* p) {
  return __builtin_bit_cast(bf16x8, *reinterpret_cast<const u16x8*>(p));
}
DI void stbf8(unsigned short* p, bf16x8 v) {
  *reinterpret_cast<u16x8*>(p) = __builtin_bit_cast(u16x8, v);
}
DI f32x8 up8(bf16x8 v) { return __builtin_convertvector(v, f32x8); }
DI f32x8 up8u(u16x8 v) { return up8(__builtin_bit_cast(bf16x8, v)); }
DI bf16x8 dn8(f32x8 v) { return __builtin_convertvector(v, bf16x8); }
DI float bfh2f(unsigned short h) { return __builtin_bit_cast(float, (unsigned)h << 16); }
DI unsigned short f2bfh(float f) {
  __bf16 b = (__bf16)f;
  return __builtin_bit_cast(unsigned short, b);
}

// ---------------- pre-convert kernels ----------------
__global__ void k_padcvt8(const float* __restrict__ in, unsigned short* __restrict__ out,
                          int nrows, int kin, int kpad) {
  long long total = (long long)nrows * (kpad / 8);
  long long i = (long long)blockIdx.x * blockDim.x + threadIdx.x;
  if (i >= total) return;
  int row = (int)(i / (kpad / 8));
  int k0 = (int)(i - (long long)row * (kpad / 8)) * 8;
  const float* src = in + (long long)row * kin;
  f32x8 v;
#pragma unroll
  for (int e = 0; e < 8; e++) v[e] = (k0 + e < kin) ? src[k0 + e] : 0.f;
  stbf8(out + (long long)row * kpad + k0, dn8(v));
}

// out[n][k] = W[k+rowoff][n], zero-padded past K
__global__ void k_transw(const float* __restrict__ W, unsigned short* __restrict__ out,
                         int K, int kpad, int rowoff) {
  int i = blockIdx.x * blockDim.x + threadIdx.x;
  if (i >= 256 * kpad) return;
  int n = i / kpad, k = i - n * kpad;
  float v = (k < K) ? W[(long long)(k + rowoff) * 256 + n] : 0.f;
  out[i] = f2bfh(v);
}

// ---------------- gather-sum over a2b (6 neighbors) ----------------
__global__ __launch_bounds__(256) void k_gathersum(
    const unsigned short* __restrict__ src, const int* __restrict__ a2b,
    unsigned short* __restrict__ out, int relu_flag) {
  int tid = blockIdx.x * 256 + threadIdx.x;
  if (tid >= cNA * 16) return;
  int atom = tid >> 4, ch = tid & 15;            // 16 threads per atom, 16 cols each
  const int* ab = a2b + (long long)atom * 6;
  int bidx[6];
#pragma unroll
  for (int j = 0; j < 6; j++) bidx[j] = ab[j];
  u16x8 r0[6], r1[6];
#pragma unroll
  for (int j = 0; j < 6; j++) {
    const unsigned short* p = src + (long long)bidx[j] * 256 + ch * 16;
    r0[j] = *reinterpret_cast<const u16x8*>(p);
    r1[j] = *reinterpret_cast<const u16x8*>(p + 8);
  }
  f32x8 lo = {0.f,0.f,0.f,0.f,0.f,0.f,0.f,0.f}, hi = lo;
#pragma unroll
  for (int j = 0; j < 6; j++) {
    f32x8 x0 = up8u(r0[j]);
    f32x8 x1 = up8u(r1[j]);
    if (relu_flag) {
#pragma unroll
      for (int e = 0; e < 8; e++) { x0[e] = fmaxf(x0[e], 0.f); x1[e] = fmaxf(x1[e], 0.f); }
    }
#pragma unroll
    for (int e = 0; e < 8; e++) { lo[e] += x0[e]; hi[e] += x1[e]; }
  }
  unsigned short* q = out + (long long)atom * 256 + ch * 16;
  stbf8(q, dn8(lo));
  stbf8(q + 8, dn8(hi));
}

// ---------------- MFMA GEMM family (16x16x32, operand-swapped) ----------------
// Block: 16 waves x 16 rows = 256 rows; N=256 as 16 col-tiles of 16.
// 2 stages of 8 col-tiles; per-stage LDS = KP=256: 64KB (2 blocks/CU), KP=160: 40KB.
// Fragment-contiguous LDS: frag (ctl,f) at (ctl*NF+f)*512 ushorts; lane reads
// frag_base + lane*8 (stride-1, conflict-free).
// Operand swap: D^T[n][r] = sum_k Wt[n][k] X[r][k]; A-op = Wt (i=n=lane&15),
// B-op = X (j=r=lane&15), k=(lane>>4)*8+jj for both. D: r=lane&15 (output row,
// FIXED per lane), n=(lane>>4)*4+q (4 consecutive output cols) -> 8-B vector
// C-loads/stores.
enum { MODE_BF16OUT = 0, MODE_MSG = 2, MODE_FINAL = 3 };

template <int KP, int MODE, bool RELU_SRC>
__global__ __launch_bounds__(1024, 8) void k_gemm(
    const unsigned short* __restrict__ A,     // direct A [nrows][KP] (or amsg for MSG)
    const unsigned short* __restrict__ Msg,   // MSG: message source [NB][256]
    const int* __restrict__ b2a, const int* __restrict__ b2revb,
    const unsigned short* __restrict__ Wt,    // [256][KP] (W transposed)
    const unsigned short* __restrict__ Cbf,   // MSG: inp ; FINAL: pf
    const float* __restrict__ bias,           // FINAL: b_o
    unsigned short* __restrict__ OutBf, int nrows) {
  constexpr int NF = KP / 32;                 // K-frags per col-tile
  constexpr int CTS = 8;                      // col-tiles per stage
  constexpr bool HASC = (MODE == MODE_MSG || MODE == MODE_FINAL);
  __shared__ unsigned short lds[CTS * NF * 512];

  const int tid = threadIdx.x;
  const int lane = tid & 63, wid = tid >> 6;
  const int wrow0 = blockIdx.x * 256 + wid * 16;
  const int rA = wrow0 + (lane & 15);
  const bool valid = rA < nrows;
  const int rS = valid ? rA : 0;
  const int koff = (lane >> 4) * 8;           // k-chunk within 32-K fragment
  const int cg = (lane >> 4) * 4;             // this lane's 4-col group within a tile

  // ---- X fragments (B-operand), held across both stages ----
  bf16x8 af[NF];
  if (MODE == MODE_MSG) {
    int ib = b2a[rS];
    int irv = b2revb[rS];
    const unsigned short* pa = A + (long long)ib * 256;
    const unsigned short* pm = Msg + (long long)irv * 256;
#pragma unroll
    for (int h = 0; h < NF / 4; h++) {
      u16x8 rawa[4], rawm[4];
#pragma unroll
      for (int t = 0; t < 4; t++) {
        int off = (h * 4 + t) * 32 + koff;
        rawa[t] = *reinterpret_cast<const u16x8*>(pa + off);
        rawm[t] = *reinterpret_cast<const u16x8*>(pm + off);
      }
#pragma unroll
      for (int t = 0; t < 4; t++) {
        f32x8 xa = up8u(rawa[t]);
        f32x8 xm = up8u(rawm[t]);
        if (RELU_SRC) {
#pragma unroll
          for (int e = 0; e < 8; e++) xm[e] = fmaxf(xm[e], 0.f);
        }
        af[h * 4 + t] = dn8(xa - xm);
      }
    }
  } else {
    const unsigned short* pa = A + (long long)rS * KP;
#pragma unroll
    for (int f = 0; f < NF; f++) af[f] = ldbf8(pa + f * 32 + koff);
  }

  const long long crow = (long long)rS * 256;
  const long long orow = (long long)rA * 256;

#pragma unroll 1
  for (int stage = 0; stage < 2; stage++) {
    // prefetch first C-tile of this stage before the barrier (latency overlaps staging)
    u16x4 cr_cur, cr_nxt;
    if (HASC)
      cr_cur = *reinterpret_cast<const u16x4*>(Cbf + crow + stage * 128 + cg);

    if (stage) __syncthreads();   // previous stage's LDS reads must finish
    for (int c = tid; c < CTS * NF * 64; c += 1024) {
      int frag = c >> 6, slot = c & 63;
      int ctl = frag / NF, f = frag - ctl * NF;
      int col = stage * 128 + ctl * 16 + (slot & 15);
      int ko = f * 32 + (slot >> 4) * 8;
      *reinterpret_cast<u16x8*>(lds + c * 8) =
          *reinterpret_cast<const u16x8*>(Wt + (long long)col * KP + ko);
    }
    __syncthreads();

#pragma unroll 1
    for (int ctl = 0; ctl < CTS; ctl++) {
      const int colg = stage * 128 + ctl * 16 + cg;   // first of 4 consecutive cols

      // prefetch next tile's C (waitcnt sinks past this tile's MFMA chain)
      if (HASC && ctl + 1 < CTS)
        cr_nxt = *reinterpret_cast<const u16x4*>(Cbf + crow + colg + 16);

      f32x4 bias4;
      if (MODE == MODE_FINAL) bias4 = *reinterpret_cast<const f32x4*>(bias + colg);

      f32x4 acc = {0.f, 0.f, 0.f, 0.f};
      const unsigned short* lb = lds + ctl * NF * 512 + lane * 8;
#pragma unroll
      for (int f = 0; f < NF; f++) {
        bf16x8 w = ldbf8(lb + f * 512);
        acc = __builtin_amdgcn_mfma_f32_16x16x32_bf16(w, af[f], acc, 0, 0, 0);
      }

      if (valid) {
        u16x4 o;
#pragma unroll
        for (int q = 0; q < 4; q++) {
          float v = acc[q];
          if (MODE == MODE_MSG) {
            v += bfh2f(cr_cur[q]);
            v = fmaxf(v, 0.f);
          } else if (MODE == MODE_FINAL) {
            v += bfh2f(cr_cur[q]) + bias4[q];
            v = fmaxf(v, 0.f);
          }
          o[q] = f2bfh(v);
        }
        *reinterpret_cast<u16x4*>(OutBf + orow + colg) = o;
      }
      cr_cur = cr_nxt;
    }
  }
}

// ---------------- molecule mean-pool (bf16 in, fp32 out) ----------------
__global__ __launch_bounds__(256) void k_meanpool(const unsigned short* __restrict__ ah,
                                                  float* __restrict__ out) {
  int m = blockIdx.x, c = threadIdx.x;
  unsigned short r[20];
#pragma unroll
  for (int i = 0; i < 20; i++) r[i] = ah[(long long)(1 + m * 20 + i) * 256 + c];
  float s = 0.f;
#pragma unroll
  for (int i = 0; i < 20; i++) s += bfh2f(r[i]);
  out[(long long)m * 256 + c] = s * 0.05f;
}

extern "C" void kernel_launch(void* const* d_in, const int* in_sizes, int n_in,
                              void* d_out, int out_size, void* d_ws, size_t ws_size,
                              hipStream_t stream) {
  const float* f_atoms = (const float*)d_in[0];
  const float* f_bonds = (const float*)d_in[1];
  const int* a2b = (const int*)d_in[2];
  const int* b2a = (const int*)d_in[3];
  const int* b2revb = (const int*)d_in[4];
  const float* W_i = (const float*)d_in[5];
  const float* W_h = (const float*)d_in[6];
  const float* W_o = (const float*)d_in[7];
  const float* b_o = (const float*)d_in[8];
  float* out = (float*)d_out;

  char* ws = (char*)d_ws;
  size_t off = 0;
  auto alloc = [&](size_t b) { size_t o = off; off += (b + 1023) & ~(size_t)1023; return o; };
  size_t o_fb = alloc((size_t)cNB * KP_F * 2);     // fb16; later reused for amsg
  size_t o_fa = alloc((size_t)cNA * KP_F * 2);     // fa16
  size_t o_inp = alloc((size_t)cNB * 256 * 2);     // inp bf16
  size_t o_bufA = alloc((size_t)cNB * 256 * 2);    // msgA ; later pf (bf16 NA*256)
  size_t o_bufB = alloc((size_t)cNB * 256 * 2);    // msgB ; later ah (bf16 NA*256)
  size_t o_wti = alloc((size_t)256 * KP_F * 2);
  size_t o_wth = alloc((size_t)256 * 256 * 2);
  size_t o_wo1 = alloc((size_t)256 * KP_F * 2);
  size_t o_wo2 = alloc((size_t)256 * 256 * 2);

  unsigned short* fb16 = (unsigned short*)(ws + o_fb);
  unsigned short* amsg = (unsigned short*)(ws + o_fb);  // overlays fb16 after K1
  unsigned short* fa16 = (unsigned short*)(ws + o_fa);
  unsigned short* inp = (unsigned short*)(ws + o_inp);
  unsigned short* msgA = (unsigned short*)(ws + o_bufA);
  unsigned short* msgB = (unsigned short*)(ws + o_bufB);
  unsigned short* pf = (unsigned short*)(ws + o_bufA);
  unsigned short* ah = (unsigned short*)(ws + o_bufB);
  unsigned short* Wti = (unsigned short*)(ws + o_wti);
  unsigned short* Wth = (unsigned short*)(ws + o_wth);
  unsigned short* Wto1 = (unsigned short*)(ws + o_wo1);
  unsigned short* Wto2 = (unsigned short*)(ws + o_wo2);

  dim3 b256(256);
  {
    long long t = (long long)cNB * (KP_F / 8);
    k_padcvt8<<<(unsigned)((t + 255) / 256), b256, 0, stream>>>(f_bonds, fb16, cNB, cBF, KP_F);
  }
  {
    long long t = (long long)cNA * (KP_F / 8);
    k_padcvt8<<<(unsigned)((t + 255) / 256), b256, 0, stream>>>(f_atoms, fa16, cNA, cAF, KP_F);
  }
  k_transw<<<(256 * KP_F + 255) / 256, b256, 0, stream>>>(W_i, Wti, cBF, KP_F, 0);
  k_transw<<<(256 * 256 + 255) / 256, b256, 0, stream>>>(W_h, Wth, 256, 256, 0);
  k_transw<<<(256 * KP_F + 255) / 256, b256, 0, stream>>>(W_o, Wto1, cAF, KP_F, 0);
  k_transw<<<(256 * 256 + 255) / 256, b256, 0, stream>>>(W_o, Wto2, 256, 256, cAF);

  const int gB = (cNB + 255) / 256;
  const int gA = (cNA + 255) / 256;
  const int gS = (cNA * 16 + 255) / 256;

  // K1: inp = fb16 @ W_i
  k_gemm<KP_F, MODE_BF16OUT, false><<<gB, 1024, 0, stream>>>(
      fb16, nullptr, nullptr, nullptr, Wti, nullptr, nullptr, inp, cNB);
  // iter 1
  k_gathersum<<<gS, b256, 0, stream>>>(inp, a2b, amsg, 1);
  k_gemm<256, MODE_MSG, true><<<gB, 1024, 0, stream>>>(
      amsg, inp, b2a, b2revb, Wth, inp, nullptr, msgA, cNB);
  // iter 2
  k_gathersum<<<gS, b256, 0, stream>>>(msgA, a2b, amsg, 0);
  k_gemm<256, MODE_MSG, false><<<gB, 1024, 0, stream>>>(
      amsg, msgA, b2a, b2revb, Wth, inp, nullptr, msgB, cNB);
  // readout
  k_gathersum<<<gS, b256, 0, stream>>>(msgB, a2b, amsg, 0);
  k_gemm<KP_F, MODE_BF16OUT, false><<<gA, 1024, 0, stream>>>(
      fa16, nullptr, nullptr, nullptr, Wto1, nullptr, nullptr, pf, cNA);
  k_gemm<256, MODE_FINAL, false><<<gA, 1024, 0, stream>>>(
      amsg, nullptr, nullptr, nullptr, Wto2, pf, b_o, ah, cNA);
  k_meanpool<<<6000, b256, 0, stream>>>(ah, out);
}